// Round 3
// baseline (148.904 us; speedup 1.0000x reference)
//
#include <hip/hip_runtime.h>
#include <hip/hip_bf16.h>
#include <stdint.h>

// Problem constants (fixed by setup_inputs):
//   features (B=128, U=100000) f32; positions (U,2) f32; neighborhoods (NN=100, K=500) i32
//   N_RUNS=10, choice = jax.random.randint(key(42), (10,), 0, 100)  -> host Threefry
#define U_DIM 100000
#define B_DIM 128
#define K_DIM 500
#define NRUNS 10
#define KPAD  512
#define TILE  32
#define NTILES 16                          // ceil(500/32)
#define NTILEPAIRS (NTILES * (NTILES + 1) / 2)   // 136
#define NPAIRWAVES (NTILEPAIRS * NRUNS)          // 1360

typedef __attribute__((ext_vector_type(8))) short short8;   // 8 bf16 (4 VGPRs)
typedef __attribute__((ext_vector_type(4))) float f32x4;    // MFMA C/D

struct ChoiceArgs { int c[NRUNS]; };

// ---------------------------------------------------------------------------
// Kernel 1: per (run, neighbor k): gather feature column, normalize in fp32
// (subtract batch mean, divide by L2 norm), store as bf16 row [k][b] for MFMA.
// One wave per (r,k); lane b and b+64 handle the two halves of B=128.
// Also zeroes the accumulators and the completion counter.
// ---------------------------------------------------------------------------
__global__ __launch_bounds__(256) void prep_kernel(
    const float* __restrict__ feat, const float* __restrict__ pos,
    const int* __restrict__ neigh, __hip_bfloat16* __restrict__ xnb,
    float2* __restrict__ npos, double* __restrict__ accum,
    unsigned* __restrict__ done, ChoiceArgs ch)
{
  if (blockIdx.x == 0) {
    if (threadIdx.x < NRUNS * 5) accum[threadIdx.x] = 0.0;
    if (threadIdx.x == NRUNS * 5) *done = 0u;
  }

  int gw   = (blockIdx.x * 256 + threadIdx.x) >> 6;   // global wave id
  int lane = threadIdx.x & 63;
  if (gw >= NRUNS * K_DIM) return;
  int r = gw / K_DIM;
  int k = gw - r * K_DIM;

  int ind = neigh[ch.c[r] * K_DIM + k];
  float f0 = feat[(size_t)lane        * U_DIM + ind];
  float f1 = feat[(size_t)(lane + 64) * U_DIM + ind];

  float s = f0 + f1;
  #pragma unroll
  for (int off = 32; off; off >>= 1) s += __shfl_xor(s, off);
  float mean = s * (1.0f / 128.0f);

  float a0 = f0 - mean, a1 = f1 - mean;
  float q = a0 * a0 + a1 * a1;
  #pragma unroll
  for (int off = 32; off; off >>= 1) q += __shfl_xor(q, off);
  float inv = rsqrtf(q);

  size_t base = ((size_t)r * KPAD + k) * B_DIM;
  xnb[base + lane]      = __float2bfloat16(a0 * inv);
  xnb[base + lane + 64] = __float2bfloat16(a1 * inv);
  if (lane == 0) npos[r * KPAD + k] = make_float2(pos[2 * ind], pos[2 * ind + 1]);
}

// ---------------------------------------------------------------------------
// Kernel 2: one WAVE per 32x32 lower-triangle tile pair. corr via
// mfma_f32_16x16x32_bf16, fragments loaded directly from global (L2-hot,
// no LDS, no barriers). A-frag lane layout: A[m=lane&15][k=quad*8+j];
// B-frag: B[k=quad*8+j][n=lane&15] = xn[j0+n][k] -> identical addressing.
// C/D: row = quad*4+reg, col = lane&15 (m89/m91-verified mapping).
// Pearson sums shuffle-reduced per wave -> 5 double atomics. Last wave
// (device-scope counter) computes the final loss.
// ---------------------------------------------------------------------------
__global__ __launch_bounds__(256) void pair_kernel(
    const __hip_bfloat16* __restrict__ xnb, const float2* __restrict__ npos,
    double* __restrict__ accum, unsigned* __restrict__ done,
    float* __restrict__ out)
{
  int gw   = (blockIdx.x * 256 + threadIdx.x) >> 6;
  int lane = threadIdx.x & 63;
  if (gw >= NPAIRWAVES) return;

  int r = gw / NTILEPAIRS;
  int p = gw - r * NTILEPAIRS;           // p = ti*(ti+1)/2 + tj, ti >= tj
  int ti = 0;
  while ((ti + 1) * (ti + 2) / 2 <= p) ti++;
  int tj = p - ti * (ti + 1) / 2;
  int i0 = ti * TILE, j0 = tj * TILE;

  const __hip_bfloat16* xr = xnb + (size_t)r * KPAD * B_DIM;
  int quad = lane >> 4, l16 = lane & 15;

  f32x4 acc00 = {}, acc01 = {}, acc10 = {}, acc11 = {};

  #pragma unroll
  for (int kk = 0; kk < 4; kk++) {
    int kb = kk * 32 + quad * 8;
    short8 a0 = *(const short8*)(xr + (size_t)(i0 + l16)      * B_DIM + kb);
    short8 a1 = *(const short8*)(xr + (size_t)(i0 + 16 + l16) * B_DIM + kb);
    short8 b0 = *(const short8*)(xr + (size_t)(j0 + l16)      * B_DIM + kb);
    short8 b1 = *(const short8*)(xr + (size_t)(j0 + 16 + l16) * B_DIM + kb);
    acc00 = __builtin_amdgcn_mfma_f32_16x16x32_bf16(a0, b0, acc00, 0, 0, 0);
    acc01 = __builtin_amdgcn_mfma_f32_16x16x32_bf16(a0, b1, acc01, 0, 0, 0);
    acc10 = __builtin_amdgcn_mfma_f32_16x16x32_bf16(a1, b0, acc10, 0, 0, 0);
    acc11 = __builtin_amdgcn_mfma_f32_16x16x32_bf16(a1, b1, acc11, 0, 0, 0);
  }

  // per-lane Pearson partial sums over its 16 (row,col) values
  const float2* pr = npos + r * KPAD;
  float sa = 0.f, sb = 0.f, saa = 0.f, sbb = 0.f, sab = 0.f;

  int gj0v = j0 + l16, gj1v = j0 + 16 + l16;
  float2 pj0 = pr[(gj0v < K_DIM) ? gj0v : 0];
  float2 pj1 = pr[(gj1v < K_DIM) ? gj1v : 0];

  #pragma unroll
  for (int tis = 0; tis < 2; tis++) {
    #pragma unroll
    for (int reg = 0; reg < 4; reg++) {
      int gi = i0 + tis * 16 + quad * 4 + reg;
      if (gi >= K_DIM) continue;
      float2 pi = pr[gi];
      // tjs = 0
      if (gj0v < K_DIM && gi > gj0v) {
        float resp = tis ? acc10[reg] : acc00[reg];
        float dx = pi.x - pj0.x, dy = pi.y - pj0.y;
        float ds = 1.0f / (sqrtf(dx * dx + dy * dy) + 1.0f);
        sa += resp; sb += ds; saa += resp * resp; sbb += ds * ds; sab += resp * ds;
      }
      // tjs = 1
      if (gj1v < K_DIM && gi > gj1v) {
        float resp = tis ? acc11[reg] : acc01[reg];
        float dx = pi.x - pj1.x, dy = pi.y - pj1.y;
        float ds = 1.0f / (sqrtf(dx * dx + dy * dy) + 1.0f);
        sa += resp; sb += ds; saa += resp * resp; sbb += ds * ds; sab += resp * ds;
      }
    }
  }

  #pragma unroll
  for (int off = 32; off; off >>= 1) {
    sa  += __shfl_xor(sa,  off);
    sb  += __shfl_xor(sb,  off);
    saa += __shfl_xor(saa, off);
    sbb += __shfl_xor(sbb, off);
    sab += __shfl_xor(sab, off);
  }

  if (lane == 0) {
    atomicAdd(&accum[r * 5 + 0], (double)sa);
    atomicAdd(&accum[r * 5 + 1], (double)sb);
    atomicAdd(&accum[r * 5 + 2], (double)saa);
    atomicAdd(&accum[r * 5 + 3], (double)sbb);
    atomicAdd(&accum[r * 5 + 4], (double)sab);
    __threadfence();                       // make accum atomics visible device-wide
    unsigned old = atomicAdd(done, 1u);
    if (old == NPAIRWAVES - 1) {
      // last wave: compute the final loss (fused finalize)
      const double n = (double)(K_DIM * (K_DIM - 1) / 2);   // 124750
      double total = 0.0;
      for (int rr_ = 0; rr_ < NRUNS; rr_++) {
        double sa_  = atomicAdd(&accum[rr_ * 5 + 0], 0.0);
        double sb_  = atomicAdd(&accum[rr_ * 5 + 1], 0.0);
        double saa_ = atomicAdd(&accum[rr_ * 5 + 2], 0.0);
        double sbb_ = atomicAdd(&accum[rr_ * 5 + 3], 0.0);
        double sab_ = atomicAdd(&accum[rr_ * 5 + 4], 0.0);
        double cov = sab_ - sa_ * sb_ / n;
        double va  = saa_ - sa_ * sa_ / n;
        double vb  = sbb_ - sb_ * sb_ / n;
        double rv  = cov / sqrt(va * vb);
        total += (1.0 - rv) * 0.5;
      }
      out[0] = (float)(total / NRUNS);
    }
  }
}

// ---------------------------------------------------------------------------
// Host: JAX Threefry-2x32 to reproduce choice = randint(key(42), (10,), 0, 100)
// ---------------------------------------------------------------------------
static inline uint32_t rotl32_host(uint32_t x, int r) { return (x << r) | (x >> (32 - r)); }

static void tf2x32(uint32_t k0, uint32_t k1, uint32_t c0, uint32_t c1,
                   uint32_t& o0, uint32_t& o1)
{
  const uint32_t rots[2][4] = {{13, 15, 26, 6}, {17, 29, 16, 24}};
  uint32_t ks[3] = {k0, k1, k0 ^ k1 ^ 0x1BD11BDAu};
  uint32_t x0 = c0 + ks[0], x1 = c1 + ks[1];
  for (int i = 0; i < 5; i++) {
    const uint32_t* rr = rots[i & 1];
    for (int j = 0; j < 4; j++) {
      x0 += x1;
      x1 = rotl32_host(x1, (int)rr[j]);
      x1 ^= x0;
    }
    x0 += ks[(i + 1) % 3];
    x1 += ks[(i + 2) % 3] + (uint32_t)(i + 1);
  }
  o0 = x0; o1 = x1;
}

extern "C" void kernel_launch(void* const* d_in, const int* in_sizes, int n_in,
                              void* d_out, int out_size, void* d_ws, size_t ws_size,
                              hipStream_t stream)
{
  const float* feat  = (const float*)d_in[0];
  const float* pos   = (const float*)d_in[1];
  const int*   neigh = (const int*)d_in[2];
  float* out = (float*)d_out;

  // --- reproduce jax.random.randint(jax.random.key(42), (10,), 0, 100) ---
  ChoiceArgs ch;
  uint32_t A0, B0, A1, B1;
  tf2x32(0u, 42u, 0u, 2u, A0, B0);
  tf2x32(0u, 42u, 1u, 3u, A1, B1);
  uint32_t hi[NRUNS], lo[NRUNS];
  for (int e = 0; e < 5; e++) {
    uint32_t h0, h1, l0, l1;
    tf2x32(A0, A1, (uint32_t)e, (uint32_t)(e + 5), h0, h1);
    hi[e] = h0; hi[e + 5] = h1;
    tf2x32(B0, B1, (uint32_t)e, (uint32_t)(e + 5), l0, l1);
    lo[e] = l0; lo[e + 5] = l1;
  }
  // span=100: multiplier = (2^16 % 100)^2 % 100 = 96
  for (int e = 0; e < NRUNS; e++)
    ch.c[e] = (int)(((hi[e] % 100u) * 96u + (lo[e] % 100u)) % 100u);

  // --- workspace layout ---
  char* ws = (char*)d_ws;
  __hip_bfloat16* xnb = (__hip_bfloat16*)ws;                       // 10*512*128 bf16 = 1.31 MB
  size_t off0 = (size_t)NRUNS * KPAD * B_DIM * sizeof(__hip_bfloat16);
  float2* npos  = (float2*)(ws + off0);                            // 10*512 float2 = 40 KB
  double* accum = (double*)(ws + off0 + (size_t)NRUNS * KPAD * sizeof(float2));
  unsigned* done = (unsigned*)(accum + NRUNS * 5);

  prep_kernel<<<dim3((NRUNS * K_DIM) / 4), 256, 0, stream>>>(feat, pos, neigh, xnb, npos, accum, done, ch);
  pair_kernel<<<dim3(NPAIRWAVES / 4), 256, 0, stream>>>(xnb, npos, accum, done, out);
}

// Round 4
// 103.210 us; speedup vs baseline: 1.4427x; 1.4427x over previous
//
#include <hip/hip_runtime.h>
#include <hip/hip_bf16.h>
#include <stdint.h>

// Problem constants (fixed by setup_inputs):
//   features (B=128, U=100000) f32; positions (U,2) f32; neighborhoods (NN=100, K=500) i32
//   N_RUNS=10, choice = jax.random.randint(key(42), (10,), 0, 100)  -> host Threefry
#define U_DIM 100000
#define B_DIM 128
#define K_DIM 500
#define NRUNS 10
#define KPAD  512
#define TILE  32
#define NTILES 16                                // ceil(500/32)
#define NTILEPAIRS (NTILES * (NTILES + 1) / 2)   // 136
#define NPAIRWAVES (NTILEPAIRS * NRUNS)          // 1360

typedef __attribute__((ext_vector_type(8))) short short8;   // 8 bf16 (4 VGPRs)
typedef __attribute__((ext_vector_type(4))) float f32x4;    // MFMA C/D

struct ChoiceArgs { int c[NRUNS]; };

// ---------------------------------------------------------------------------
// Kernel 1: per (run, neighbor k): gather feature column, normalize in fp32
// (single fused reduction: S=Σx, SS=Σx²; mean=S/128, q=SS−S²/128), store as
// bf16 row [k][b] for MFMA. One wave per (r,k).
// ---------------------------------------------------------------------------
__global__ __launch_bounds__(256) void prep_kernel(
    const float* __restrict__ feat, const float* __restrict__ pos,
    const int* __restrict__ neigh, __hip_bfloat16* __restrict__ xnb,
    float2* __restrict__ npos, ChoiceArgs ch)
{
  int gw   = (blockIdx.x * 256 + threadIdx.x) >> 6;   // global wave id
  int lane = threadIdx.x & 63;
  if (gw >= NRUNS * K_DIM) return;
  int r = gw / K_DIM;
  int k = gw - r * K_DIM;

  int ind = neigh[ch.c[r] * K_DIM + k];
  float f0 = feat[(size_t)lane        * U_DIM + ind];
  float f1 = feat[(size_t)(lane + 64) * U_DIM + ind];

  float s  = f0 + f1;
  float ss = f0 * f0 + f1 * f1;
  #pragma unroll
  for (int off = 32; off; off >>= 1) {   // single fused chain for both sums
    s  += __shfl_xor(s,  off);
    ss += __shfl_xor(ss, off);
  }
  float mean = s * (1.0f / 128.0f);
  float q    = ss - s * mean;            // Σ(x-mean)² = Σx² − S²/128
  float inv  = rsqrtf(q);

  size_t base = ((size_t)r * KPAD + k) * B_DIM;
  xnb[base + lane]      = __float2bfloat16((f0 - mean) * inv);
  xnb[base + lane + 64] = __float2bfloat16((f1 - mean) * inv);
  if (lane == 0) npos[r * KPAD + k] = make_float2(pos[2 * ind], pos[2 * ind + 1]);
}

// ---------------------------------------------------------------------------
// Kernel 2: one WAVE per 32x32 lower-triangle tile pair. corr via
// mfma_f32_16x16x32_bf16, fragments loaded directly from global (L2-hot,
// no LDS, no barriers, NO ATOMICS). Per-wave Pearson partials (Sa,Sb,Saa,
// Sbb,Sab) shuffle-reduced, then stored to a private ws slot.
// ---------------------------------------------------------------------------
__global__ __launch_bounds__(256) void pair_kernel(
    const __hip_bfloat16* __restrict__ xnb, const float2* __restrict__ npos,
    float* __restrict__ part)
{
  int gw   = (blockIdx.x * 256 + threadIdx.x) >> 6;
  int lane = threadIdx.x & 63;
  if (gw >= NPAIRWAVES) return;

  int r = gw / NTILEPAIRS;
  int p = gw - r * NTILEPAIRS;           // p = ti*(ti+1)/2 + tj, ti >= tj
  int ti = 0;
  while ((ti + 1) * (ti + 2) / 2 <= p) ti++;
  int tj = p - ti * (ti + 1) / 2;
  int i0 = ti * TILE, j0 = tj * TILE;

  const __hip_bfloat16* xr = xnb + (size_t)r * KPAD * B_DIM;
  int quad = lane >> 4, l16 = lane & 15;

  f32x4 acc00 = {}, acc01 = {}, acc10 = {}, acc11 = {};

  #pragma unroll
  for (int kk = 0; kk < 4; kk++) {
    int kb = kk * 32 + quad * 8;
    short8 a0 = *(const short8*)(xr + (size_t)(i0 + l16)      * B_DIM + kb);
    short8 a1 = *(const short8*)(xr + (size_t)(i0 + 16 + l16) * B_DIM + kb);
    short8 b0 = *(const short8*)(xr + (size_t)(j0 + l16)      * B_DIM + kb);
    short8 b1 = *(const short8*)(xr + (size_t)(j0 + 16 + l16) * B_DIM + kb);
    acc00 = __builtin_amdgcn_mfma_f32_16x16x32_bf16(a0, b0, acc00, 0, 0, 0);
    acc01 = __builtin_amdgcn_mfma_f32_16x16x32_bf16(a0, b1, acc01, 0, 0, 0);
    acc10 = __builtin_amdgcn_mfma_f32_16x16x32_bf16(a1, b0, acc10, 0, 0, 0);
    acc11 = __builtin_amdgcn_mfma_f32_16x16x32_bf16(a1, b1, acc11, 0, 0, 0);
  }

  // per-lane Pearson partial sums over its 16 (row,col) values
  // C/D layout: row = quad*4+reg, col = lane&15 (m89/m91-verified)
  const float2* pr = npos + r * KPAD;
  float sa = 0.f, sb = 0.f, saa = 0.f, sbb = 0.f, sab = 0.f;

  int gj0v = j0 + l16, gj1v = j0 + 16 + l16;
  float2 pj0 = pr[(gj0v < K_DIM) ? gj0v : 0];
  float2 pj1 = pr[(gj1v < K_DIM) ? gj1v : 0];

  #pragma unroll
  for (int tis = 0; tis < 2; tis++) {
    #pragma unroll
    for (int reg = 0; reg < 4; reg++) {
      int gi = i0 + tis * 16 + quad * 4 + reg;
      if (gi >= K_DIM) continue;
      float2 pi = pr[gi];
      if (gj0v < K_DIM && gi > gj0v) {
        float resp = tis ? acc10[reg] : acc00[reg];
        float dx = pi.x - pj0.x, dy = pi.y - pj0.y;
        float ds = 1.0f / (sqrtf(dx * dx + dy * dy) + 1.0f);
        sa += resp; sb += ds; saa += resp * resp; sbb += ds * ds; sab += resp * ds;
      }
      if (gj1v < K_DIM && gi > gj1v) {
        float resp = tis ? acc11[reg] : acc01[reg];
        float dx = pi.x - pj1.x, dy = pi.y - pj1.y;
        float ds = 1.0f / (sqrtf(dx * dx + dy * dy) + 1.0f);
        sa += resp; sb += ds; saa += resp * resp; sbb += ds * ds; sab += resp * ds;
      }
    }
  }

  #pragma unroll
  for (int off = 32; off; off >>= 1) {
    sa  += __shfl_xor(sa,  off);
    sb  += __shfl_xor(sb,  off);
    saa += __shfl_xor(saa, off);
    sbb += __shfl_xor(sbb, off);
    sab += __shfl_xor(sab, off);
  }

  if (lane == 0) {
    float* slot = part + (size_t)gw * 5;   // private slot: zero contention
    slot[0] = sa; slot[1] = sb; slot[2] = saa; slot[3] = sbb; slot[4] = sab;
  }
}

// ---------------------------------------------------------------------------
// Kernel 3: 1 block, 10 waves. Wave r reduces the 136 partial-sum slots of
// run r in double, computes Pearson r -> loss; thread 0 averages runs.
// ---------------------------------------------------------------------------
__global__ __launch_bounds__(640) void finalize_kernel(
    const float* __restrict__ part, float* __restrict__ out)
{
  __shared__ double contrib[NRUNS];
  int wave = threadIdx.x >> 6;    // = run
  int lane = threadIdx.x & 63;

  double v[5] = {0, 0, 0, 0, 0};
  for (int p = lane; p < NTILEPAIRS; p += 64) {
    const float* slot = part + ((size_t)wave * NTILEPAIRS + p) * 5;
    #pragma unroll
    for (int i = 0; i < 5; i++) v[i] += (double)slot[i];
  }
  #pragma unroll
  for (int off = 32; off; off >>= 1) {
    #pragma unroll
    for (int i = 0; i < 5; i++) v[i] += __shfl_xor(v[i], off);
  }
  if (lane == 0) {
    const double n = (double)(K_DIM * (K_DIM - 1) / 2);   // 124750
    double cov = v[4] - v[0] * v[1] / n;
    double va  = v[2] - v[0] * v[0] / n;
    double vb  = v[3] - v[1] * v[1] / n;
    contrib[wave] = (1.0 - cov / sqrt(va * vb)) * 0.5;
  }
  __syncthreads();
  if (threadIdx.x == 0) {
    double total = 0.0;
    #pragma unroll
    for (int r = 0; r < NRUNS; r++) total += contrib[r];
    out[0] = (float)(total / NRUNS);
  }
}

// ---------------------------------------------------------------------------
// Host: JAX Threefry-2x32 to reproduce choice = randint(key(42), (10,), 0, 100)
// ---------------------------------------------------------------------------
static inline uint32_t rotl32_host(uint32_t x, int r) { return (x << r) | (x >> (32 - r)); }

static void tf2x32(uint32_t k0, uint32_t k1, uint32_t c0, uint32_t c1,
                   uint32_t& o0, uint32_t& o1)
{
  const uint32_t rots[2][4] = {{13, 15, 26, 6}, {17, 29, 16, 24}};
  uint32_t ks[3] = {k0, k1, k0 ^ k1 ^ 0x1BD11BDAu};
  uint32_t x0 = c0 + ks[0], x1 = c1 + ks[1];
  for (int i = 0; i < 5; i++) {
    const uint32_t* rr = rots[i & 1];
    for (int j = 0; j < 4; j++) {
      x0 += x1;
      x1 = rotl32_host(x1, (int)rr[j]);
      x1 ^= x0;
    }
    x0 += ks[(i + 1) % 3];
    x1 += ks[(i + 2) % 3] + (uint32_t)(i + 1);
  }
  o0 = x0; o1 = x1;
}

extern "C" void kernel_launch(void* const* d_in, const int* in_sizes, int n_in,
                              void* d_out, int out_size, void* d_ws, size_t ws_size,
                              hipStream_t stream)
{
  const float* feat  = (const float*)d_in[0];
  const float* pos   = (const float*)d_in[1];
  const int*   neigh = (const int*)d_in[2];
  float* out = (float*)d_out;

  // --- reproduce jax.random.randint(jax.random.key(42), (10,), 0, 100) ---
  ChoiceArgs ch;
  uint32_t A0, B0, A1, B1;
  tf2x32(0u, 42u, 0u, 2u, A0, B0);
  tf2x32(0u, 42u, 1u, 3u, A1, B1);
  uint32_t hi[NRUNS], lo[NRUNS];
  for (int e = 0; e < 5; e++) {
    uint32_t h0, h1, l0, l1;
    tf2x32(A0, A1, (uint32_t)e, (uint32_t)(e + 5), h0, h1);
    hi[e] = h0; hi[e + 5] = h1;
    tf2x32(B0, B1, (uint32_t)e, (uint32_t)(e + 5), l0, l1);
    lo[e] = l0; lo[e + 5] = l1;
  }
  // span=100: multiplier = (2^16 % 100)^2 % 100 = 96
  for (int e = 0; e < NRUNS; e++)
    ch.c[e] = (int)(((hi[e] % 100u) * 96u + (lo[e] % 100u)) % 100u);

  // --- workspace layout ---
  char* ws = (char*)d_ws;
  __hip_bfloat16* xnb = (__hip_bfloat16*)ws;                 // 10*512*128 bf16 = 1.31 MB
  size_t off0 = (size_t)NRUNS * KPAD * B_DIM * sizeof(__hip_bfloat16);
  float2* npos = (float2*)(ws + off0);                       // 10*512 float2 = 40 KB
  float*  part = (float*)(ws + off0 + (size_t)NRUNS * KPAD * sizeof(float2));  // 1360*5 f32

  prep_kernel<<<dim3((NRUNS * K_DIM) / 4), 256, 0, stream>>>(feat, pos, neigh, xnb, npos, ch);
  pair_kernel<<<dim3(NPAIRWAVES / 4), 256, 0, stream>>>(xnb, npos, part);
  finalize_kernel<<<dim3(1), 640, 0, stream>>>(part, out);
}